// Round 15
// baseline (155.831 us; speedup 1.0000x reference)
//
#include <hip/hip_runtime.h>
#include <hip/hip_bf16.h>

// B=8, C_IN=C_OUT=64, H=W=64, K=3, N=9, PAD=1; padded coords in [0,65]
// f32 in, f32 out. Semantics identical to R5-R14 (verified).
// R15 = R14 + (a) XCD-pinning: b = blockIdx.x & 7 so all 64 blocks of a batch
// land on one XCD's L2 (1MB x-set fits 4MB L2; was 8MB thrash), and
// (b) Phase-D g/q register cache + full unroll (VGPR 64->~118, cap 128).

typedef unsigned int u32;
typedef unsigned short u16;
typedef short s8v __attribute__((ext_vector_type(8)));     // 8 bf16 (4 VGPR)
typedef float f4v __attribute__((ext_vector_type(4)));     // MFMA acc

__device__ __forceinline__ u16 f2bf(float f) {
  u32 u = __builtin_bit_cast(u32, f);
  u32 r = (u + 0x7FFFu + ((u >> 16) & 1u)) >> 16;   // RNE, finite inputs
  return (u16)r;
}

// ---------- k0: weight prep ----------
__global__ __launch_bounds__(256) void k0_prep(
    const float* __restrict__ wconv,  // [64][576]
    const float* __restrict__ woff,   // [18][64][9]
    u16* __restrict__ wfrag,          // 4*18*64*8 = 36864 bf16
    float* __restrict__ woff_r) {     // 64*216 f32
  int tid = blockIdx.x * 256 + threadIdx.x;   // grid 72*256 = 18432
  if (tid < 4608) {
    int nt = tid / 1152, ks = (tid / 64) % 18, lane = tid & 63;
    int co = nt * 16 + (lane & 15);
    int k0 = ks * 32 + ((lane >> 4) << 3);
    const float* src = wconv + co * 576 + k0;
    u16* dst = wfrag + tid * 8;
    #pragma unroll
    for (int j = 0; j < 8; ++j) dst[j] = f2bf(src[j]);
  }
  if (tid < 10368) {
    int o = tid / 576, c = (tid / 9) % 64, k = tid % 9;
    woff_r[c * 216 + o * 12 + k] = woff[tid];
  }
}

// ---------- fused main: one block per (b,h), 512 blocks x 512 threads ----------
__global__ __launch_bounds__(512, 4) void deform_one(
    const float* __restrict__ x,        // [8][64][64][64]
    const float* __restrict__ woff_r,   // [64][18][12] f32
    const float* __restrict__ boff,     // [18]
    const u16*  __restrict__ wfrag,     // B-fragments bf16
    float* __restrict__ out) {          // [8][64][64][64]
  __shared__ __align__(16) u16 xos[64 * 296];  // 37888B: Phase-B partials (f32) then xo bf16 [64][296]
  __shared__ float4 gw[576];      // 9216B [n][w]
  __shared__ u32    qq[576];      // 2304B [n][w]
  __shared__ float  offs_s[1152]; // 4608B [o][w]      total 54016B

  int bh = blockIdx.x;
  int b = bh & 7;                 // XCD-pinned: round-robin dispatch puts all
  int h = bh >> 3;                // blocks of batch b on XCD b -> L2 locality
  int t = threadIdx.x;
  int wlane = t & 63;
  int wv = __builtin_amdgcn_readfirstlane(t >> 6);   // 0..7
  const float* xb = x + b * 262144;

  // ---- Phase B: offset conv, wave wv owns channels [8wv, 8wv+8) ----
  {
    int w = wlane;
    bool lf = w > 0, rt = w < 63;
    float acc[18];
    #pragma unroll
    for (int o = 0; o < 18; ++o) acc[o] = 0.f;

    for (int cl = 0; cl < 8; ++cl) {
      int c = wv * 8 + cl;
      const float* xc = xb + c * 4096;
      float v[9];
      #pragma unroll
      for (int kh = 0; kh < 3; ++kh) {
        int hh = h + kh - 1;
        bool vr = (hh >= 0 && hh < 64);
        const float* row = xc + hh * 64;
        v[kh * 3 + 0] = (vr && lf) ? row[w - 1] : 0.f;
        v[kh * 3 + 1] = vr         ? row[w]     : 0.f;
        v[kh * 3 + 2] = (vr && rt) ? row[w + 1] : 0.f;
      }
      const float4* wc4 = (const float4*)(woff_r + c * 216);  // wave-uniform -> s_load
      #pragma unroll
      for (int o = 0; o < 18; ++o) {
        float4 wa  = wc4[o * 3 + 0];
        float4 wb  = wc4[o * 3 + 1];
        float4 wcv = wc4[o * 3 + 2];
        acc[o] += v[0]*wa.x + v[1]*wa.y + v[2]*wa.z + v[3]*wa.w
                + v[4]*wb.x + v[5]*wb.y + v[6]*wb.z + v[7]*wb.w
                + v[8]*wcv.x;
      }
    }

    float* part = (float*)xos;                 // 4 regions x 1152 f32
    if (wv >= 4) {
      float* reg = part + (wv - 4) * 1152;
      #pragma unroll
      for (int o = 0; o < 18; ++o)
        reg[o * 64 + w] = acc[o];
    }
    __syncthreads();
    if (wv < 4) {
      float* reg = part + wv * 1152;
      #pragma unroll
      for (int o = 0; o < 18; ++o)
        reg[o * 64 + w] += acc[o];
    }
    __syncthreads();
    for (int i = t; i < 1152; i += 512) {
      int o = i >> 6;
      offs_s[i] = boff[o] + part[i] + part[1152 + i] + part[2304 + i] + part[3456 + i];
    }
  }
  __syncthreads();

  // ---- Phase C: corners + bilinear weights, validity folded ----
  for (int p = t; p < 576; p += 512) {
    int n  = p >> 6;       // p = n*64 + w
    int ww = p & 63;
    float ox = offs_s[n * 64 + ww];
    float oy = offs_s[(9 + n) * 64 + ww];
    float px = (float)(h + (n / 3)) + ox;   // (h+1)+(n/3-1)+ox
    float py = (float)(ww + (n % 3)) + oy;
    float fx = floorf(px), fy = floorf(py);
    float pxc  = fminf(fmaxf(px, 0.f), 65.f);
    float pyc  = fminf(fmaxf(py, 0.f), 65.f);
    float fltx = fminf(fmaxf(fx, 0.f), 65.f);
    float flty = fminf(fmaxf(fy, 0.f), 65.f);
    float frbx = fminf(fmaxf(fx + 1.f, 0.f), 65.f);
    float frby = fminf(fmaxf(fy + 1.f, 0.f), 65.f);
    float ax = 1.f + fltx - pxc, bx = 1.f - frbx + pxc;
    float ay = 1.f + flty - pyc, by = 1.f - frby + pyc;
    float glt = ax * ay, grb = bx * by, glb = ax * by, grt = bx * ay;

    int ilt = (int)fltx, jlt = (int)flty, irb = (int)frbx, jrb = (int)frby;
    bool bi0 = (ilt >= 1 && ilt <= 64), bj0 = (jlt >= 1 && jlt <= 64);
    bool bi1 = (irb >= 1 && irb <= 64), bj1 = (jrb >= 1 && jrb <= 64);
    u32 i0 = bi0 ? (u32)(ilt - 1) : 0u;
    u32 j0 = bj0 ? (u32)(jlt - 1) : 0u;
    u32 i1 = bi1 ? (u32)(irb - 1) : 0u;
    u32 j1 = bj1 ? (u32)(jrb - 1) : 0u;
    gw[p] = make_float4((bi0 && bj0) ? glt : 0.f, (bi1 && bj1) ? grb : 0.f,
                        (bi0 && bj1) ? glb : 0.f, (bi1 && bj0) ? grt : 0.f);
    qq[p] = i0 | (j0 << 8) | (i1 << 16) | (j1 << 24);
  }
  __syncthreads();

  // ---- Phase D: register-cache this lane's 9 g/q, then 2 slices ----
  float4 g[9];
  u32    oLT[9], oRB[9], oLB[9], oRT[9];
  #pragma unroll
  for (int n = 0; n < 9; ++n) {
    g[n] = gw[n * 64 + wlane];
    u32 q = qq[n * 64 + wlane];
    u32 i0 = q & 255, j0 = (q >> 8) & 255, i1 = (q >> 16) & 255, j1 = q >> 24;
    oLT[n] = i0 * 64 + j0;  oRB[n] = i1 * 64 + j1;
    oLB[n] = i0 * 64 + j1;  oRT[n] = i1 * 64 + j0;
  }

  int m0 = wv & 3;                      // w-tile
  int n0 = (wv >> 2) * 2;               // co-tiles n0, n0+1
  int aoff = (m0 * 16 + (wlane & 15)) * 296 + ((wlane >> 4) << 3);
  const s8v* Wf = (const s8v*)wfrag;    // [(nt*18+ks)*64 + lane]
  f4v acc0 = {0.f, 0.f, 0.f, 0.f}, acc1 = {0.f, 0.f, 0.f, 0.f};

  for (int s = 0; s < 2; ++s) {
    int c_l0 = wv * 4;
    const float* xc0 = xb + (s * 32 + c_l0) * 4096;
    #pragma unroll
    for (int n = 0; n < 9; ++n) {
      #pragma unroll
      for (int j = 0; j < 4; ++j) {
        const float* xc = xc0 + j * 4096;
        float v = g[n].x * xc[oLT[n]] + g[n].y * xc[oRB[n]]
                + g[n].z * xc[oLB[n]] + g[n].w * xc[oRT[n]];
        xos[wlane * 296 + (c_l0 + j) * 9 + n] = f2bf(v);
      }
    }
    __syncthreads();

    #pragma unroll
    for (int ksl = 0; ksl < 9; ++ksl) {
      s8v a = *(const s8v*)(xos + aoff + ksl * 32);
      int ks = s * 9 + ksl;
      s8v b0 = Wf[(n0 * 18 + ks) * 64 + wlane];
      s8v b1 = Wf[((n0 + 1) * 18 + ks) * 64 + wlane];
      acc0 = __builtin_amdgcn_mfma_f32_16x16x32_bf16(a, b0, acc0, 0, 0, 0);
      acc1 = __builtin_amdgcn_mfma_f32_16x16x32_bf16(a, b1, acc1, 0, 0, 0);
    }
    __syncthreads();
  }

  // ---- store: D layout col=lane&15 (co), row=quad*4+reg (w) ----
  float* ob = out + b * 262144 + h * 64;
  int quad = wlane >> 4;
  int w_b  = m0 * 16 + quad * 4;
  int co0  = n0 * 16 + (wlane & 15);
  int co1  = co0 + 16;
  #pragma unroll
  for (int r = 0; r < 4; ++r) {
    ob[co0 * 4096 + w_b + r] = acc0[r];
    ob[co1 * 4096 + w_b + r] = acc1[r];
  }
}

extern "C" void kernel_launch(void* const* d_in, const int* in_sizes, int n_in,
                              void* d_out, int out_size, void* d_ws, size_t ws_size,
                              hipStream_t stream) {
  const float *x = nullptr, *woff = nullptr, *boff = nullptr, *wconv = nullptr;
  for (int i = 0; i < n_in; ++i) {
    switch (in_sizes[i]) {
      case 2097152: x     = (const float*)d_in[i]; break;
      case 10368:   woff  = (const float*)d_in[i]; break;
      case 18:      boff  = (const float*)d_in[i]; break;
      case 36864:   wconv = (const float*)d_in[i]; break;
      default: break;
    }
  }
  if (!x)     x     = (const float*)d_in[0];
  if (!woff)  woff  = (const float*)d_in[1];
  if (!boff)  boff  = (const float*)d_in[2];
  if (!wconv) wconv = (const float*)d_in[3];
  float* out = (float*)d_out;

  u16*   wfrag  = (u16*)d_ws;                       // 73728 B
  float* woff_r = (float*)((char*)d_ws + 73728);    // 55296 B

  k0_prep<<<72, 256, 0, stream>>>(wconv, woff, wfrag, woff_r);
  deform_one<<<512, 512, 0, stream>>>(x, woff_r, boff, wfrag, out);
}

// Round 16
// 148.393 us; speedup vs baseline: 1.0501x; 1.0501x over previous
//
#include <hip/hip_runtime.h>
#include <hip/hip_bf16.h>

// B=8, C_IN=C_OUT=64, H=W=64, K=3, N=9, PAD=1; padded coords in [0,65]
// f32 in, f32 out. Semantics identical to R5-R15 (verified).
// R16 = R14 + XCD pinning (b = blockIdx.x & 7) ONLY.
// R15's g/q register arrays (72 VGPRs) spilled to scratch (WRITE 9->35MB);
// reverted to R14's per-n LDS reads. Pinning kept: FETCH 43->19.5MB.

typedef unsigned int u32;
typedef unsigned short u16;
typedef short s8v __attribute__((ext_vector_type(8)));     // 8 bf16 (4 VGPR)
typedef float f4v __attribute__((ext_vector_type(4)));     // MFMA acc

__device__ __forceinline__ u16 f2bf(float f) {
  u32 u = __builtin_bit_cast(u32, f);
  u32 r = (u + 0x7FFFu + ((u >> 16) & 1u)) >> 16;   // RNE, finite inputs
  return (u16)r;
}

// ---------- k0: weight prep ----------
__global__ __launch_bounds__(256) void k0_prep(
    const float* __restrict__ wconv,  // [64][576]
    const float* __restrict__ woff,   // [18][64][9]
    u16* __restrict__ wfrag,          // 4*18*64*8 = 36864 bf16
    float* __restrict__ woff_r) {     // 64*216 f32
  int tid = blockIdx.x * 256 + threadIdx.x;   // grid 72*256 = 18432
  if (tid < 4608) {
    int nt = tid / 1152, ks = (tid / 64) % 18, lane = tid & 63;
    int co = nt * 16 + (lane & 15);
    int k0 = ks * 32 + ((lane >> 4) << 3);
    const float* src = wconv + co * 576 + k0;
    u16* dst = wfrag + tid * 8;
    #pragma unroll
    for (int j = 0; j < 8; ++j) dst[j] = f2bf(src[j]);
  }
  if (tid < 10368) {
    int o = tid / 576, c = (tid / 9) % 64, k = tid % 9;
    woff_r[c * 216 + o * 12 + k] = woff[tid];
  }
}

// ---------- fused main: one block per (b,h), 512 blocks x 512 threads ----------
__global__ __launch_bounds__(512, 4) void deform_one(
    const float* __restrict__ x,        // [8][64][64][64]
    const float* __restrict__ woff_r,   // [64][18][12] f32
    const float* __restrict__ boff,     // [18]
    const u16*  __restrict__ wfrag,     // B-fragments bf16
    float* __restrict__ out) {          // [8][64][64][64]
  __shared__ __align__(16) u16 xos[64 * 296];  // 37888B: Phase-B partials (f32) then xo bf16 [64][296]
  __shared__ float4 gw[576];      // 9216B [n][w]
  __shared__ u32    qq[576];      // 2304B [n][w]
  __shared__ float  offs_s[1152]; // 4608B [o][w]      total 54016B

  int bh = blockIdx.x;
  int b = bh & 7;                 // XCD-pinned: round-robin dispatch puts all
  int h = bh >> 3;                // blocks of batch b on XCD b -> L2 locality
  int t = threadIdx.x;
  int wlane = t & 63;
  int wv = __builtin_amdgcn_readfirstlane(t >> 6);   // 0..7
  const float* xb = x + b * 262144;

  // ---- Phase B: offset conv, wave wv owns channels [8wv, 8wv+8) ----
  {
    int w = wlane;
    bool lf = w > 0, rt = w < 63;
    float acc[18];
    #pragma unroll
    for (int o = 0; o < 18; ++o) acc[o] = 0.f;

    for (int cl = 0; cl < 8; ++cl) {
      int c = wv * 8 + cl;
      const float* xc = xb + c * 4096;
      float v[9];
      #pragma unroll
      for (int kh = 0; kh < 3; ++kh) {
        int hh = h + kh - 1;
        bool vr = (hh >= 0 && hh < 64);
        const float* row = xc + hh * 64;
        v[kh * 3 + 0] = (vr && lf) ? row[w - 1] : 0.f;
        v[kh * 3 + 1] = vr         ? row[w]     : 0.f;
        v[kh * 3 + 2] = (vr && rt) ? row[w + 1] : 0.f;
      }
      const float4* wc4 = (const float4*)(woff_r + c * 216);  // wave-uniform -> s_load
      #pragma unroll
      for (int o = 0; o < 18; ++o) {
        float4 wa  = wc4[o * 3 + 0];
        float4 wb  = wc4[o * 3 + 1];
        float4 wcv = wc4[o * 3 + 2];
        acc[o] += v[0]*wa.x + v[1]*wa.y + v[2]*wa.z + v[3]*wa.w
                + v[4]*wb.x + v[5]*wb.y + v[6]*wb.z + v[7]*wb.w
                + v[8]*wcv.x;
      }
    }

    float* part = (float*)xos;                 // 4 regions x 1152 f32
    if (wv >= 4) {
      float* reg = part + (wv - 4) * 1152;
      #pragma unroll
      for (int o = 0; o < 18; ++o)
        reg[o * 64 + w] = acc[o];
    }
    __syncthreads();
    if (wv < 4) {
      float* reg = part + wv * 1152;
      #pragma unroll
      for (int o = 0; o < 18; ++o)
        reg[o * 64 + w] += acc[o];
    }
    __syncthreads();
    for (int i = t; i < 1152; i += 512) {
      int o = i >> 6;
      offs_s[i] = boff[o] + part[i] + part[1152 + i] + part[2304 + i] + part[3456 + i];
    }
  }
  __syncthreads();

  // ---- Phase C: corners + bilinear weights, validity folded ----
  for (int p = t; p < 576; p += 512) {
    int n  = p >> 6;       // p = n*64 + w
    int ww = p & 63;
    float ox = offs_s[n * 64 + ww];
    float oy = offs_s[(9 + n) * 64 + ww];
    float px = (float)(h + (n / 3)) + ox;   // (h+1)+(n/3-1)+ox
    float py = (float)(ww + (n % 3)) + oy;
    float fx = floorf(px), fy = floorf(py);
    float pxc  = fminf(fmaxf(px, 0.f), 65.f);
    float pyc  = fminf(fmaxf(py, 0.f), 65.f);
    float fltx = fminf(fmaxf(fx, 0.f), 65.f);
    float flty = fminf(fmaxf(fy, 0.f), 65.f);
    float frbx = fminf(fmaxf(fx + 1.f, 0.f), 65.f);
    float frby = fminf(fmaxf(fy + 1.f, 0.f), 65.f);
    float ax = 1.f + fltx - pxc, bx = 1.f - frbx + pxc;
    float ay = 1.f + flty - pyc, by = 1.f - frby + pyc;
    float glt = ax * ay, grb = bx * by, glb = ax * by, grt = bx * ay;

    int ilt = (int)fltx, jlt = (int)flty, irb = (int)frbx, jrb = (int)frby;
    bool bi0 = (ilt >= 1 && ilt <= 64), bj0 = (jlt >= 1 && jlt <= 64);
    bool bi1 = (irb >= 1 && irb <= 64), bj1 = (jrb >= 1 && jrb <= 64);
    u32 i0 = bi0 ? (u32)(ilt - 1) : 0u;
    u32 j0 = bj0 ? (u32)(jlt - 1) : 0u;
    u32 i1 = bi1 ? (u32)(irb - 1) : 0u;
    u32 j1 = bj1 ? (u32)(jrb - 1) : 0u;
    gw[p] = make_float4((bi0 && bj0) ? glt : 0.f, (bi1 && bj1) ? grb : 0.f,
                        (bi0 && bj1) ? glb : 0.f, (bi1 && bj0) ? grt : 0.f);
    qq[p] = i0 | (j0 << 8) | (i1 << 16) | (j1 << 24);
  }
  __syncthreads();

  // ---- Phase D: 2 slices of 32 c: sample -> xo bf16 [w][k], MFMA dot ----
  int m0 = wv & 3;                      // w-tile
  int n0 = (wv >> 2) * 2;               // co-tiles n0, n0+1
  int aoff = (m0 * 16 + (wlane & 15)) * 296 + ((wlane >> 4) << 3);
  const s8v* Wf = (const s8v*)wfrag;    // [(nt*18+ks)*64 + lane]
  f4v acc0 = {0.f, 0.f, 0.f, 0.f}, acc1 = {0.f, 0.f, 0.f, 0.f};

  for (int s = 0; s < 2; ++s) {
    // sample: thread covers c_l = wv*4 .. wv*4+3, its lane's w, all 9 n
    int c_l0 = wv * 4;
    const float* xc0 = xb + (s * 32 + c_l0) * 4096;
    for (int n = 0; n < 9; ++n) {
      float4 g = gw[n * 64 + wlane];
      u32 q    = qq[n * 64 + wlane];
      int i0 = q & 255, j0 = (q >> 8) & 255, i1 = (q >> 16) & 255, j1 = q >> 24;
      int olt = i0 * 64 + j0, orb = i1 * 64 + j1;
      int olb = i0 * 64 + j1, ort = i1 * 64 + j0;
      #pragma unroll
      for (int j = 0; j < 4; ++j) {
        const float* xc = xc0 + j * 4096;
        float v = g.x * xc[olt] + g.y * xc[orb] + g.z * xc[olb] + g.w * xc[ort];
        xos[wlane * 296 + (c_l0 + j) * 9 + n] = f2bf(v);
      }
    }
    __syncthreads();

    // dot: 9 K-steps of 32; A from LDS (b128), B from global (coalesced 16B/lane)
    #pragma unroll
    for (int ksl = 0; ksl < 9; ++ksl) {
      s8v a = *(const s8v*)(xos + aoff + ksl * 32);
      int ks = s * 9 + ksl;
      s8v b0 = Wf[(n0 * 18 + ks) * 64 + wlane];
      s8v b1 = Wf[((n0 + 1) * 18 + ks) * 64 + wlane];
      acc0 = __builtin_amdgcn_mfma_f32_16x16x32_bf16(a, b0, acc0, 0, 0, 0);
      acc1 = __builtin_amdgcn_mfma_f32_16x16x32_bf16(a, b1, acc1, 0, 0, 0);
    }
    __syncthreads();
  }

  // ---- store: D layout col=lane&15 (co), row=quad*4+reg (w) ----
  float* ob = out + b * 262144 + h * 64;
  int quad = wlane >> 4;
  int w_b  = m0 * 16 + quad * 4;
  int co0  = n0 * 16 + (wlane & 15);
  int co1  = co0 + 16;
  #pragma unroll
  for (int r = 0; r < 4; ++r) {
    ob[co0 * 4096 + w_b + r] = acc0[r];
    ob[co1 * 4096 + w_b + r] = acc1[r];
  }
}

extern "C" void kernel_launch(void* const* d_in, const int* in_sizes, int n_in,
                              void* d_out, int out_size, void* d_ws, size_t ws_size,
                              hipStream_t stream) {
  const float *x = nullptr, *woff = nullptr, *boff = nullptr, *wconv = nullptr;
  for (int i = 0; i < n_in; ++i) {
    switch (in_sizes[i]) {
      case 2097152: x     = (const float*)d_in[i]; break;
      case 10368:   woff  = (const float*)d_in[i]; break;
      case 18:      boff  = (const float*)d_in[i]; break;
      case 36864:   wconv = (const float*)d_in[i]; break;
      default: break;
    }
  }
  if (!x)     x     = (const float*)d_in[0];
  if (!woff)  woff  = (const float*)d_in[1];
  if (!boff)  boff  = (const float*)d_in[2];
  if (!wconv) wconv = (const float*)d_in[3];
  float* out = (float*)d_out;

  u16*   wfrag  = (u16*)d_ws;                       // 73728 B
  float* woff_r = (float*)((char*)d_ws + 73728);    // 55296 B

  k0_prep<<<72, 256, 0, stream>>>(wconv, woff, wfrag, woff_r);
  deform_one<<<512, 512, 0, stream>>>(x, woff_r, boff, wfrag, out);
}